// Round 1
// baseline (953.800 us; speedup 1.0000x reference)
//
#include <hip/hip_runtime.h>
#include <stdint.h>

#define DIMN 1024
#define HIDN 64

typedef __attribute__((ext_vector_type(8))) short bf16x8;
typedef __attribute__((ext_vector_type(4))) float f32x4;

__device__ __forceinline__ unsigned short f2bf(float f) {
    union { float f; unsigned int u; } v; v.f = f;
    unsigned int u = v.u;
    u += 0x7fffu + ((u >> 16) & 1u);   // round-to-nearest-even
    return (unsigned short)(u >> 16);
}

__device__ __forceinline__ float geluf(float x) {
    return 0.5f * x * (1.0f + erff(x * 0.70710678118654752f));
}
__device__ __forceinline__ float dgeluf(float x) {
    float c = 0.5f * (1.0f + erff(x * 0.70710678118654752f));
    return c + x * 0.3989422804014327f * expf(-0.5f * x * x);
}

// ---------------- prep kernels ----------------

__global__ void w2sum_kernel(const float* __restrict__ W2, float* __restrict__ w2sum) {
    // one block, 256 threads: w2sum[k] = sum_i W2[k][i]
    __shared__ float part[4][64];
    int k = threadIdx.x & 63, c = threadIdx.x >> 6;
    float s = 0.f;
    const float* row = W2 + (size_t)k * DIMN + c * 256;
    for (int j = 0; j < 256; ++j) s += row[j];
    part[c][k] = s;
    __syncthreads();
    if (c == 0) w2sum[k] = part[0][k] + part[1][k] + part[2][k] + part[3][k];
}

__global__ void prep_kernel(const float* __restrict__ W1, const float* __restrict__ W2,
                            const float* __restrict__ mass, const float* __restrict__ dtp,
                            unsigned short* __restrict__ W1bf,   // [2048][64]
                            unsigned short* __restrict__ W1Tbf,  // [64][2048]
                            unsigned short* __restrict__ W2Tbf,  // [1024][64]
                            float* __restrict__ dtm) {
    int gid = blockIdx.x * blockDim.x + threadIdx.x;
    int nt = gridDim.x * blockDim.x;
    for (int i = gid; i < 2048 * 64; i += nt) {
        unsigned short b = f2bf(W1[i]);
        W1bf[i] = b;
        int k = i >> 6, n = i & 63;
        W1Tbf[n * 2048 + k] = b;
    }
    for (int i = gid; i < 64 * 1024; i += nt) {
        int k = i >> 10, n = i & 1023;
        W2Tbf[n * 64 + k] = f2bf(W2[i]);
    }
    float dt = 1.0f / (1.0f + expf(-dtp[0]));
    for (int i = gid; i < DIMN; i += nt) dtm[i] = dt / mass[i];
}

// ---------------- fused leapfrog kernel ----------------
// 16 rows per block, 256 threads (4 waves). Waves split the HID=64 cols (z phases)
// or the DIM=1024 cols (wide phases). All MFMA 16x16x32 bf16, fp32 accumulate.

__global__ __launch_bounds__(256)
void fused_kernel(const float* __restrict__ q, const float* __restrict__ p,
                  const float* __restrict__ b1, const float* __restrict__ dtp,
                  const unsigned short* __restrict__ W1bf,
                  const unsigned short* __restrict__ W1Tbf,
                  const unsigned short* __restrict__ W2Tbf,
                  const float* __restrict__ w2sum, const float* __restrict__ dtm,
                  float* __restrict__ outq, float* __restrict__ outp,
                  float* __restrict__ oute) {
    __shared__ unsigned short stage[16][1032];  // bf16 row stage, +8 pad (bank stride 4)
    __shared__ float h1s[16][65];               // gelu(z1), fp32
    __shared__ unsigned short us[16][72];       // bf16 A-operand for wide phases

    const int tid  = threadIdx.x;
    const int lane = tid & 63;
    const int wv   = tid >> 6;
    const int quad = lane >> 4;
    const int l16  = lane & 15;
    const int rowbase = blockIdx.x * 16;

    const float dt  = 1.0f / (1.0f + expf(-dtp[0]));
    const float hdt = 0.5f * dt;

    // stage 16 rows of fp32 src into bf16 LDS (coalesced float4 reads)
    auto stage_rows = [&](const float* src) {
        const float* base = src + (size_t)rowbase * DIMN + 4 * tid;
        #pragma unroll 4
        for (int r = 0; r < 16; ++r) {
            float4 v = *(const float4*)(base + (size_t)r * DIMN);
            ushort4 pk = make_ushort4(f2bf(v.x), f2bf(v.y), f2bf(v.z), f2bf(v.w));
            *(ushort4*)&stage[r][4 * tid] = pk;
        }
    };

    // z = X1@W1a + X2@W1b + b1 ; mode 0: us=u1,h1s=gelu ; 1: us=u2 ; 2: us=h1-gelu(z3)
    auto zphase = [&](const float* X1, const float* X2, int mode) {
        f32x4 acc = {0.f, 0.f, 0.f, 0.f};
        const unsigned short* Wr = W1Tbf + (size_t)(16 * wv + l16) * 2048 + quad * 8;
        const unsigned short* Ar = &stage[l16][quad * 8];

        stage_rows(X1);
        __syncthreads();
        #pragma unroll
        for (int k0 = 0; k0 < 1024; k0 += 32) {
            bf16x8 a = *(const bf16x8*)(Ar + k0);
            bf16x8 b = *(const bf16x8*)(Wr + k0);
            acc = __builtin_amdgcn_mfma_f32_16x16x32_bf16(a, b, acc, 0, 0, 0);
        }
        __syncthreads();
        stage_rows(X2);
        __syncthreads();
        #pragma unroll
        for (int k0 = 0; k0 < 1024; k0 += 32) {
            bf16x8 a = *(const bf16x8*)(Ar + k0);
            bf16x8 b = *(const bf16x8*)(Wr + 1024 + k0);
            acc = __builtin_amdgcn_mfma_f32_16x16x32_bf16(a, b, acc, 0, 0, 0);
        }
        const int col = 16 * wv + l16;
        const float bb = b1[col];
        const float wsv = w2sum[col];
        #pragma unroll
        for (int rg = 0; rg < 4; ++rg) {
            int row = quad * 4 + rg;
            float z = acc[rg] + bb;
            if (mode == 0) {
                us[row][col] = f2bf(dgeluf(z) * wsv);
                h1s[row][col] = geluf(z);
            } else if (mode == 1) {
                us[row][col] = f2bf(dgeluf(z) * wsv);
            } else {
                us[row][col] = f2bf(h1s[row][col] - geluf(z));
            }
        }
        __syncthreads();
    };

    // D[16 x 1024] = us @ Bmat^T(row-major [1024][64]) ; fused elementwise epilogue
    auto widephase = [&](const unsigned short* Bmat, int mode) {
        bf16x8 a0 = *(const bf16x8*)&us[l16][quad * 8];
        bf16x8 a1 = *(const bf16x8*)&us[l16][32 + quad * 8];
        for (int t = wv; t < 64; t += 4) {
            int n0 = t * 16;
            f32x4 acc = {0.f, 0.f, 0.f, 0.f};
            const unsigned short* Br = Bmat + (size_t)(n0 + l16) * 64 + quad * 8;
            bf16x8 b0 = *(const bf16x8*)(Br);
            bf16x8 b1v = *(const bf16x8*)(Br + 32);
            acc = __builtin_amdgcn_mfma_f32_16x16x32_bf16(a0, b0, acc, 0, 0, 0);
            acc = __builtin_amdgcn_mfma_f32_16x16x32_bf16(a1, b1v, acc, 0, 0, 0);
            int i = n0 + l16;
            #pragma unroll
            for (int rg = 0; rg < 4; ++rg) {
                int row = quad * 4 + rg;
                size_t idx = (size_t)(rowbase + row) * DIMN + i;
                if (mode == 0) {            // dH_dq -> p_half, q_new
                    float ph = p[idx] - hdt * acc[rg];
                    float qn = q[idx] + dtm[i] * ph;
                    outp[idx] = ph;
                    outq[idx] = qn;
                } else if (mode == 1) {     // p_new
                    outp[idx] = outp[idx] - hdt * acc[rg];
                } else {                    // energy
                    oute[idx] = fabsf(acc[rg]);
                }
            }
        }
        __threadfence();
        __syncthreads();
    };

    zphase(q, p, 0);                // z1 -> u1, h1
    widephase(W1bf, 0);             // dH_dq -> p_half(outp), q_new(outq)
    zphase(outq, outp, 1);          // z2 -> u2
    widephase(W1bf, 1);             // p_new (outp)
    zphase(outq, outp, 2);          // z3 -> us = h1 - h3
    widephase(W2Tbf, 2);            // energy = |(h1-h3)@W2|
}

// ---------------- launch ----------------

extern "C" void kernel_launch(void* const* d_in, const int* in_sizes, int n_in,
                              void* d_out, int out_size, void* d_ws, size_t ws_size,
                              hipStream_t stream) {
    const float* q    = (const float*)d_in[0];
    const float* p    = (const float*)d_in[1];
    const float* W1   = (const float*)d_in[2];
    const float* b1   = (const float*)d_in[3];
    const float* W2   = (const float*)d_in[4];
    /* b2 = d_in[5] cancels in energy */
    const float* mass = (const float*)d_in[6];
    const float* dtp  = (const float*)d_in[7];

    float* out  = (float*)d_out;
    float* outq = out;
    float* outp = out + (size_t)16384 * 1024;
    float* oute = out + (size_t)2 * 16384 * 1024;

    char* ws = (char*)d_ws;
    unsigned short* W1bf  = (unsigned short*)(ws);            // 256 KB
    unsigned short* W1Tbf = (unsigned short*)(ws + 262144);   // 256 KB
    unsigned short* W2Tbf = (unsigned short*)(ws + 524288);   // 128 KB
    float* w2sum          = (float*)(ws + 655360);            // 256 B
    float* dtm            = (float*)(ws + 655616);            // 4 KB

    hipLaunchKernelGGL(w2sum_kernel, dim3(1), dim3(256), 0, stream, W2, w2sum);
    hipLaunchKernelGGL(prep_kernel, dim3(256), dim3(256), 0, stream,
                       W1, W2, mass, dtp, W1bf, W1Tbf, W2Tbf, dtm);
    hipLaunchKernelGGL(fused_kernel, dim3(1024), dim3(256), 0, stream,
                       q, p, b1, dtp, W1bf, W1Tbf, W2Tbf, w2sum, dtm,
                       outq, outp, oute);
}

// Round 2
// 624.997 us; speedup vs baseline: 1.5261x; 1.5261x over previous
//
#include <hip/hip_runtime.h>
#include <stdint.h>

#define BROWS 16384
#define DIMN 1024
#define HIDN 64

typedef __attribute__((ext_vector_type(8))) short bf16x8;
typedef __attribute__((ext_vector_type(4))) float f32x4;

__device__ __forceinline__ unsigned short f2bf(float f) {
    union { float f; unsigned int u; } v; v.f = f;
    unsigned int u = v.u;
    u += 0x7fffu + ((u >> 16) & 1u);   // round-to-nearest-even
    return (unsigned short)(u >> 16);
}

__device__ __forceinline__ bf16x8 pack8(float4 a, float4 b) {
    bf16x8 r;
    r[0] = (short)f2bf(a.x); r[1] = (short)f2bf(a.y);
    r[2] = (short)f2bf(a.z); r[3] = (short)f2bf(a.w);
    r[4] = (short)f2bf(b.x); r[5] = (short)f2bf(b.y);
    r[6] = (short)f2bf(b.z); r[7] = (short)f2bf(b.w);
    return r;
}

__device__ __forceinline__ float geluf(float x) {
    return 0.5f * x * (1.0f + erff(x * 0.70710678118654752f));
}
__device__ __forceinline__ float dgeluf(float x) {
    float c = 0.5f * (1.0f + erff(x * 0.70710678118654752f));
    return c + x * 0.3989422804014327f * expf(-0.5f * x * x);
}

// ---------------- prep kernels ----------------

__global__ void w2sum_kernel(const float* __restrict__ W2, float* __restrict__ w2sum) {
    __shared__ float part[4][64];
    int k = threadIdx.x & 63, c = threadIdx.x >> 6;
    float s = 0.f;
    const float* row = W2 + (size_t)k * DIMN + c * 256;
    for (int j = 0; j < 256; ++j) s += row[j];
    part[c][k] = s;
    __syncthreads();
    if (c == 0) w2sum[k] = part[0][k] + part[1][k] + part[2][k] + part[3][k];
}

__global__ void prep_kernel(const float* __restrict__ W1, const float* __restrict__ W2,
                            const float* __restrict__ mass, const float* __restrict__ dtp,
                            unsigned short* __restrict__ W1bf,   // [2048][64]
                            unsigned short* __restrict__ W1Tbf,  // [64][2048]
                            unsigned short* __restrict__ W2Tbf,  // [1024][64]
                            float* __restrict__ dtm) {
    int gid = blockIdx.x * blockDim.x + threadIdx.x;
    int nt = gridDim.x * blockDim.x;
    for (int i = gid; i < 2048 * 64; i += nt) {
        unsigned short b = f2bf(W1[i]);
        W1bf[i] = b;
        int k = i >> 6, n = i & 63;
        W1Tbf[n * 2048 + k] = b;
    }
    for (int i = gid; i < 64 * 1024; i += nt) {
        int k = i >> 10, n = i & 1023;
        W2Tbf[n * 64 + k] = f2bf(W2[i]);
    }
    float dt = 1.0f / (1.0f + expf(-dtp[0]));
    for (int i = gid; i < DIMN; i += nt) dtm[i] = dt / mass[i];
}

// ---------------- z kernel: z = [X1,X2]@W1 + b1, per-wave 16-row tile ----------------
// One wave owns 16 rows and all 64 hid cols (4 col-tiles). No LDS, no barriers.
// mode 0: u=f2bf(dgelu(z)*w2sum), h1f=gelu(z)   (z1)
// mode 1: u=f2bf(dgelu(z)*w2sum)                (z2)
// mode 2: u=f2bf(h1f - gelu(z))                 (z3 -> d)

__global__ __launch_bounds__(256)
void zkern(const float* __restrict__ X1, const float* __restrict__ X2,
           const unsigned short* __restrict__ W1T,   // [64][2048]
           const float* __restrict__ b1, const float* __restrict__ w2sum,
           unsigned short* __restrict__ uout, float* __restrict__ h1f,
           int mode) {
    const int wv = threadIdx.x >> 6, lane = threadIdx.x & 63;
    const int l16 = lane & 15, quad = lane >> 4;
    const int tile = blockIdx.x * 4 + wv;           // 0..1023
    const size_t arow = (size_t)tile * 16 + l16;
    const float* r1 = X1 + arow * DIMN;
    const float* r2 = X2 + arow * DIMN;
    const int kq = quad * 8;

    f32x4 acc[4] = {{0,0,0,0},{0,0,0,0},{0,0,0,0},{0,0,0,0}};

    #pragma unroll 4
    for (int it = 0; it < 32; ++it) {
        int k = it * 32 + kq;
        float4 a0 = *(const float4*)(r1 + k);
        float4 a1 = *(const float4*)(r1 + k + 4);
        bf16x8 af = pack8(a0, a1);
        #pragma unroll
        for (int c = 0; c < 4; ++c) {
            bf16x8 bf = *(const bf16x8*)(W1T + (size_t)(c * 16 + l16) * 2048 + k);
            acc[c] = __builtin_amdgcn_mfma_f32_16x16x32_bf16(af, bf, acc[c], 0, 0, 0);
        }
    }
    #pragma unroll 4
    for (int it = 0; it < 32; ++it) {
        int k = it * 32 + kq;
        float4 a0 = *(const float4*)(r2 + k);
        float4 a1 = *(const float4*)(r2 + k + 4);
        bf16x8 af = pack8(a0, a1);
        #pragma unroll
        for (int c = 0; c < 4; ++c) {
            bf16x8 bf = *(const bf16x8*)(W1T + (size_t)(c * 16 + l16) * 2048 + 1024 + k);
            acc[c] = __builtin_amdgcn_mfma_f32_16x16x32_bf16(af, bf, acc[c], 0, 0, 0);
        }
    }

    const int orow0 = tile * 16 + quad * 4;
    #pragma unroll
    for (int c = 0; c < 4; ++c) {
        const int col = c * 16 + l16;
        const float bb = b1[col];
        const float ws = w2sum[col];
        #pragma unroll
        for (int rg = 0; rg < 4; ++rg) {
            size_t o = (size_t)(orow0 + rg) * 64 + col;
            float z = acc[c][rg] + bb;
            if (mode == 0) {
                uout[o] = f2bf(dgeluf(z) * ws);
                h1f[o] = geluf(z);
            } else if (mode == 1) {
                uout[o] = f2bf(dgeluf(z) * ws);
            } else {
                uout[o] = f2bf(h1f[o] - geluf(z));
            }
        }
    }
}

// ---------------- wide kernel: D[16384][1024] = U @ Bt^T, fused epilogue ----------------
// One wave per 16x16 tile, K=64 -> 2 MFMAs. 65536 waves.
// mode 0: ph = p - hdt*D; outp=ph; outq = q + dtm*ph
// mode 1: outp -= hdt*D
// mode 2: outq = |D|   (energy; outq param = oute)

__global__ __launch_bounds__(256)
void widekern(const unsigned short* __restrict__ U,    // [16384][64] bf16
              const unsigned short* __restrict__ Bt,   // [1024][64] bf16
              const float* __restrict__ q, const float* __restrict__ p,
              const float* __restrict__ dtm, const float* __restrict__ dtp,
              float* __restrict__ outq, float* __restrict__ outp,
              int mode) {
    const int wv = threadIdx.x >> 6, lane = threadIdx.x & 63;
    const int l16 = lane & 15, quad = lane >> 4;
    const int gw = blockIdx.x * 4 + wv;     // 0..65535
    const int mt = gw >> 6, nt = gw & 63;
    const int kq = quad * 8;

    const size_t arow = (size_t)mt * 16 + l16;
    bf16x8 a0 = *(const bf16x8*)(U + arow * 64 + kq);
    bf16x8 a1 = *(const bf16x8*)(U + arow * 64 + 32 + kq);
    const int n0 = nt * 16;
    bf16x8 b0 = *(const bf16x8*)(Bt + (size_t)(n0 + l16) * 64 + kq);
    bf16x8 b1 = *(const bf16x8*)(Bt + (size_t)(n0 + l16) * 64 + 32 + kq);

    f32x4 acc = {0, 0, 0, 0};
    acc = __builtin_amdgcn_mfma_f32_16x16x32_bf16(a0, b0, acc, 0, 0, 0);
    acc = __builtin_amdgcn_mfma_f32_16x16x32_bf16(a1, b1, acc, 0, 0, 0);

    const int i = n0 + l16;
    const float hdt = 0.5f / (1.0f + expf(-dtp[0]));
    const float dm = (mode == 0) ? dtm[i] : 0.f;

    #pragma unroll
    for (int rg = 0; rg < 4; ++rg) {
        size_t idx = (size_t)(mt * 16 + quad * 4 + rg) * DIMN + i;
        if (mode == 0) {
            float ph = p[idx] - hdt * acc[rg];
            outp[idx] = ph;
            outq[idx] = q[idx] + dm * ph;
        } else if (mode == 1) {
            outp[idx] = outp[idx] - hdt * acc[rg];
        } else {
            outq[idx] = fabsf(acc[rg]);
        }
    }
}

// ---------------- launch ----------------

extern "C" void kernel_launch(void* const* d_in, const int* in_sizes, int n_in,
                              void* d_out, int out_size, void* d_ws, size_t ws_size,
                              hipStream_t stream) {
    const float* q    = (const float*)d_in[0];
    const float* p    = (const float*)d_in[1];
    const float* W1   = (const float*)d_in[2];
    const float* b1   = (const float*)d_in[3];
    const float* W2   = (const float*)d_in[4];
    /* b2 = d_in[5] cancels in energy */
    const float* mass = (const float*)d_in[6];
    const float* dtp  = (const float*)d_in[7];

    float* out  = (float*)d_out;
    float* outq = out;
    float* outp = out + (size_t)BROWS * DIMN;
    float* oute = out + (size_t)2 * BROWS * DIMN;

    char* ws = (char*)d_ws;
    unsigned short* W1bf  = (unsigned short*)(ws);              // 256 KB [2048][64]
    unsigned short* W1Tbf = (unsigned short*)(ws + 262144);     // 256 KB [64][2048]
    unsigned short* W2Tbf = (unsigned short*)(ws + 524288);     // 128 KB [1024][64]
    float* w2sum          = (float*)(ws + 655360);              // 256 B
    float* dtm            = (float*)(ws + 655616);              // 4 KB
    float* h1f            = (float*)(ws + 1048576);             // 4 MB [16384][64] fp32
    unsigned short* u1    = (unsigned short*)(ws + 5242880);    // 2 MB
    unsigned short* u2    = (unsigned short*)(ws + 7340032);    // 2 MB
    unsigned short* dbuf  = (unsigned short*)(ws + 9437184);    // 2 MB

    hipLaunchKernelGGL(w2sum_kernel, dim3(1), dim3(256), 0, stream, W2, w2sum);
    hipLaunchKernelGGL(prep_kernel, dim3(256), dim3(256), 0, stream,
                       W1, W2, mass, dtp, W1bf, W1Tbf, W2Tbf, dtm);

    // z1 -> u1 (bf16), h1f (fp32)
    hipLaunchKernelGGL(zkern, dim3(256), dim3(256), 0, stream,
                       q, p, W1Tbf, b1, w2sum, u1, h1f, 0);
    // wide1: p_half -> outp, q_new -> outq
    hipLaunchKernelGGL(widekern, dim3(16384), dim3(256), 0, stream,
                       u1, W1bf, q, p, dtm, dtp, outq, outp, 0);
    // z2 -> u2
    hipLaunchKernelGGL(zkern, dim3(256), dim3(256), 0, stream,
                       outq, outp, W1Tbf, b1, w2sum, u2, h1f, 1);
    // wide2: p_new -> outp
    hipLaunchKernelGGL(widekern, dim3(16384), dim3(256), 0, stream,
                       u2, W1bf, q, p, dtm, dtp, outq, outp, 1);
    // z3 -> dbuf = bf16(h1 - gelu(z3))
    hipLaunchKernelGGL(zkern, dim3(256), dim3(256), 0, stream,
                       outq, outp, W1Tbf, b1, w2sum, dbuf, h1f, 2);
    // energy: oute = |dbuf @ W2|
    hipLaunchKernelGGL(widekern, dim3(16384), dim3(256), 0, stream,
                       dbuf, W2Tbf, q, p, dtm, dtp, oute, outp, 2);
}